// Round 5
// baseline (287.578 us; speedup 1.0000x reference)
//
#include <hip/hip_runtime.h>
#include <hip/hip_bf16.h>

#define HWP 9216   // H*W
#define HH  96
#define WW  96
#define CC  256    // Cin == Cout
#define NB  2

// ============================ R14: DIAGNOSTIC BUILD ============================
// Both kernels repeat their hot loop REPS=6 times (reps 0..4 kept alive via
// asm volatile, rep 5 is the real pass -> output bit-identical). Purpose:
// inflate each kernel past the 44us top-5 rocprof cutoff so we finally get
// per-kernel dur/VALUBusy/MfmaUtil/Occupancy/FETCH. True cost ~ visible/6.
// REVERT the rep loops next round.
#define REPS 6

typedef __attribute__((ext_vector_type(8))) short bf16x8;
typedef __attribute__((ext_vector_type(4))) float f32x4;

__device__ inline unsigned short f2bf(float f) {
  union { __hip_bfloat16 h; unsigned short u; } cvt;
  cvt.h = __float2bfloat16(f);
  return cvt.u;
}
__device__ inline float bf_lo(unsigned int u) { return __uint_as_float(u << 16); }
__device__ inline float bf_hi(unsigned int u) { return __uint_as_float(u & 0xffff0000u); }

// PITFALL (R12): hipLaunchCooperativeKernel + this_grid().sync() under the
// harness graph capture does NOT provide a working grid barrier. Do NOT fuse
// across the xpb producer/consumer boundary.

__global__ __launch_bounds__(256) void k_main(const float* __restrict__ x,
                                              const float* __restrict__ pw_w,
                                              const float* __restrict__ off_w,
                                              const float* __restrict__ off_b,
                                              unsigned short* __restrict__ xpb,
                                              float* __restrict__ offs) {
  __shared__ unsigned short As[2][32 * 40];    // [pix][k] dbuf
  __shared__ unsigned short Bs[2][256 * 40];   // [n][k] dbuf; Bs[0] reused as Cs

  // XCD-aligned decode: g -> (e, b, m); strip block x = e*36 + m
  int g   = blockIdx.x;          // 0..575
  int e   = g & 7;
  int idx = g >> 3;              // 0..71
  int b   = idx / 36;
  int m   = idx - b * 36;        // 0..35
  int pix0 = (e * 36 + m) * 32;  // local pixel within batch

  int t    = threadIdx.x;
  int lane = t & 63;
  int w    = t >> 6;
  int mw = (w & 1) * 16;     // wave pixel tile
  int nw = (w >> 1) * 128;   // wave channel half
  int r = lane & 15, q = lane >> 4;

  f32x4 acc[8];

  const float* xg = x + (size_t)b * CC * HWP + pix0;
  int sc = t >> 3;           // channel within 32-chunk
  int sp = (t & 7) * 4;      // pixel offset
  int nB = t >> 2;           // B row within 64-group
  int c8 = (t & 3) * 8;      // B k-offset

#pragma unroll 1
  for (int rep = 0; rep < REPS; ++rep) {
#pragma unroll
    for (int i = 0; i < 8; ++i) acc[i] = (f32x4){};

    // ---- prologue: stage K-step 0 into buf 0 (B converted inline from f32)
    // (safe to rewrite buf0 between reps: last rep iteration ended with two
    //  barriers since buf0's final read)
    {
      f32x4 xv = __builtin_nontemporal_load((const f32x4*)(xg + (size_t)sc * HWP + sp));
      As[0][(sp + 0) * 40 + sc] = f2bf(xv.x);
      As[0][(sp + 1) * 40 + sc] = f2bf(xv.y);
      As[0][(sp + 2) * 40 + sc] = f2bf(xv.z);
      As[0][(sp + 3) * 40 + sc] = f2bf(xv.w);
#pragma unroll
      for (int rp = 0; rp < 4; ++rp) {
        int n = rp * 64 + nB;
        const float* wp = pw_w + n * 256 + c8;
        float4 w0 = *(const float4*)wp;
        float4 w1 = *(const float4*)(wp + 4);
        union { ushort4 h[2]; uint4 q4; } pk;
        pk.h[0] = make_ushort4(f2bf(w0.x), f2bf(w0.y), f2bf(w0.z), f2bf(w0.w));
        pk.h[1] = make_ushort4(f2bf(w1.x), f2bf(w1.y), f2bf(w1.z), f2bf(w1.w));
        *(uint4*)&Bs[0][n * 40 + c8] = pk.q4;
      }
    }
    __syncthreads();

    // ---- main loop: 1 barrier per K-step, prefetch t+1 overlapped with MFMA(t)
    for (int kt = 0; kt < 8; ++kt) {
      int cur = kt & 1;
      f32x4 xv;
      float4 b0[4], b1[4];
      bool pre = (kt < 7);
      if (pre) {
        int k0 = (kt + 1) * 32;
        xv = __builtin_nontemporal_load((const f32x4*)(xg + (size_t)(k0 + sc) * HWP + sp));
#pragma unroll
        for (int rp = 0; rp < 4; ++rp) {
          const float* wp = pw_w + (rp * 64 + nB) * 256 + k0 + c8;
          b0[rp] = *(const float4*)wp;
          b1[rp] = *(const float4*)(wp + 4);
        }
      }
      bf16x8 a = *(const bf16x8*)&As[cur][(mw + r) * 40 + q * 8];
#pragma unroll
      for (int nt = 0; nt < 8; ++nt) {
        bf16x8 bb = *(const bf16x8*)&Bs[cur][(nw + nt * 16 + r) * 40 + q * 8];
        acc[nt] = __builtin_amdgcn_mfma_f32_16x16x32_bf16(a, bb, acc[nt], 0, 0, 0);
      }
      if (pre) {
        int nx = cur ^ 1;
        As[nx][(sp + 0) * 40 + sc] = f2bf(xv.x);
        As[nx][(sp + 1) * 40 + sc] = f2bf(xv.y);
        As[nx][(sp + 2) * 40 + sc] = f2bf(xv.z);
        As[nx][(sp + 3) * 40 + sc] = f2bf(xv.w);
#pragma unroll
        for (int rp = 0; rp < 4; ++rp) {
          int n = rp * 64 + nB;
          union { ushort4 h[2]; uint4 q4; } pk;
          pk.h[0] = make_ushort4(f2bf(b0[rp].x), f2bf(b0[rp].y), f2bf(b0[rp].z), f2bf(b0[rp].w));
          pk.h[1] = make_ushort4(f2bf(b1[rp].x), f2bf(b1[rp].y), f2bf(b1[rp].z), f2bf(b1[rp].w));
          *(uint4*)&Bs[nx][n * 40 + c8] = pk.q4;
        }
      }
      __syncthreads();
    }

    // keep dummy reps' results alive so loads+MFMAs aren't DCE'd (rule #17)
    if (rep < REPS - 1) {
#pragma unroll
      for (int i = 0; i < 8; ++i)
        asm volatile("" :: "v"(acc[i][0]), "v"(acc[i][1]), "v"(acc[i][2]), "v"(acc[i][3]));
    }
  }

  // Cs aliases Bs[0]: last K-step read buf 1; final sync drained buf 0 reads.
  unsigned short* Cs = &Bs[0][0];   // [pix][ch] bf16, pad 264 (8448 <= 10240 shorts)

  // C/D: col = lane&15 (ch), row = q*4+rr (pix) -> Cs[pix][ch] bf16
#pragma unroll
  for (int nt = 0; nt < 8; ++nt)
#pragma unroll
    for (int rr = 0; rr < 4; ++rr)
      Cs[(mw + q * 4 + rr) * 264 + nw + nt * 16 + r] = f2bf(acc[nt][rr]);
  __syncthreads();

  // write xpb coalesced: 64 B contiguous per thread
  {
    int pix = t >> 3, c32 = (t & 7) * 32;
    unsigned short* o = xpb + ((size_t)b * HWP + pix0 + pix) * CC + c32;
#pragma unroll
    for (int j = 0; j < 4; ++j)
      *(uint4*)(o + j * 8) = *(const uint4*)&Cs[pix * 264 + c32 + j * 8];
  }

  // offset epilogue: offs[pix, o] = sum_c Cs[pix][c] * off_w[o][c] + off_b[o]
  {
    int mw2 = (w & 1) * 16;    // pixel tile
    int nw2 = (w >> 1) * 16;   // o tile (0 or 16)
    int row = nw2 + r;
    f32x4 oacc = {};
#pragma unroll
    for (int ks = 0; ks < CC; ks += 32) {
      bf16x8 a = *(const bf16x8*)&Cs[(mw2 + r) * 264 + ks + q * 8];
      bf16x8 bb = {};
      if (row < 18) {
        const float* wp = off_w + row * 256 + ks + q * 8;
        float4 w0 = *(const float4*)wp;
        float4 w1 = *(const float4*)(wp + 4);
        union { unsigned short u[8]; bf16x8 v; } pk;
        pk.u[0] = f2bf(w0.x); pk.u[1] = f2bf(w0.y); pk.u[2] = f2bf(w0.z); pk.u[3] = f2bf(w0.w);
        pk.u[4] = f2bf(w1.x); pk.u[5] = f2bf(w1.y); pk.u[6] = f2bf(w1.z); pk.u[7] = f2bf(w1.w);
        bb = pk.v;
      }
      oacc = __builtin_amdgcn_mfma_f32_16x16x32_bf16(a, bb, oacc, 0, 0, 0);
    }
    if (row < 18) {
      float ob = off_b[row];
      size_t base = ((size_t)b * HWP + pix0 + mw2 + q * 4) * 20 + row;
#pragma unroll
      for (int rr = 0; rr < 4; ++rr)
        offs[base + (size_t)rr * 20] = oacc[rr] + ob;
    }
  }
}

// ---- gather + depthwise (R10 wave-uniform precompute structure, R13 dvs LDS)
__global__ __launch_bounds__(256) void k_gather(const unsigned short* __restrict__ xp,
                                                const float* __restrict__ offs,
                                                const float* __restrict__ dw_w,
                                                float* __restrict__ out) {
  __shared__ float Cs[16][257];
  __shared__ float4 Wt[16][9];   // bilinear weights per (pixel, tap)
  __shared__ int4   Ad[16][9];   // corner row byte-offsets per (pixel, tap)
  __shared__ float  dvs[9][257]; // dw_w transposed [tap][ch]

  // XCD-aligned decode: g -> (e, b, m2); chunk c = e*72 + m2 (16 px each)
  int g   = blockIdx.x;          // 0..1151
  int e   = g & 7;
  int idx = g >> 3;              // 0..143
  int b   = idx / 72;
  int m2  = idx - b * 72;        // 0..71
  int c   = e * 72 + m2;         // 0..575
  int pix0 = b * HWP + c * 16;   // global pixel

  int wave = threadIdx.x >> 6;
  int lane = threadIdx.x & 63;
  int c0 = lane * 4;

  int hw0 = pix0 - b * HWP;
  const unsigned short* xb = xp + (size_t)b * HWP * CC;
  const float* opb = offs + (size_t)pix0 * 20;

  // ---- phase 0a: stage dw_w transposed
  {
    int t = threadIdx.x;
#pragma unroll
    for (int kk = 0; kk < 9; ++kk)
      dvs[kk][t] = dw_w[t * 9 + kk];
  }

  // ---- phase 0b: 144 threads compute the wave-uniform per-(pixel,tap) data
  {
    int tp = threadIdx.x;
    if (tp < 144) {
      int ip = tp / 9;               // pixel 0..15
      int kk = tp - ip * 9;          // tap 0..8
      int hw = hw0 + ip;
      int h = hw / WW;
      int wq = hw - h * WW;
      float2 o2 = *(const float2*)(opb + ip * 20 + 2 * kk);
      float y = (float)(h + kk / 3 - 1) + o2.x;
      float x = (float)(wq + kk % 3 - 1) + o2.y;
      float y0f = floorf(y), x0f = floorf(x);
      float fy = y - y0f, fx = x - x0f;
      int y0 = (int)y0f, x0 = (int)x0f;
      int y1 = y0 + 1, x1 = x0 + 1;
      bool vy0 = (y0 >= 0) & (y0 < HH);
      bool vy1 = (y1 >= 0) & (y1 < HH);
      bool vx0 = (x0 >= 0) & (x0 < WW);
      bool vx1 = (x1 >= 0) & (x1 < WW);
      int y0c = y0 < 0 ? 0 : (y0 > HH - 1 ? HH - 1 : y0);
      int y1c = y1 < 0 ? 0 : (y1 > HH - 1 ? HH - 1 : y1);
      int x0c = x0 < 0 ? 0 : (x0 > WW - 1 ? WW - 1 : x0);
      int x1c = x1 < 0 ? 0 : (x1 > WW - 1 ? WW - 1 : x1);
      Wt[ip][kk] = make_float4(
          (1.f - fy) * (1.f - fx) * ((vy0 && vx0) ? 1.f : 0.f),
          (1.f - fy) * fx         * ((vy0 && vx1) ? 1.f : 0.f),
          fy * (1.f - fx)         * ((vy1 && vx0) ? 1.f : 0.f),
          fy * fx                 * ((vy1 && vx1) ? 1.f : 0.f));
      Ad[ip][kk] = make_int4((y0c * WW + x0c) * (CC * 2), (y0c * WW + x1c) * (CC * 2),
                             (y1c * WW + x0c) * (CC * 2), (y1c * WW + x1c) * (CC * 2));
    }
  }
  __syncthreads();

  const char* xbc = (const char*)xb;
  unsigned lb = (unsigned)(lane * 8);   // this lane's 4-channel byte offset

#pragma unroll 1
  for (int rep = 0; rep < REPS; ++rep) {
    float acc[4][4] = {};
#pragma unroll
    for (int kk = 0; kk < 9; ++kk) {
      float4 dv = *(const float4*)&dvs[kk][c0];
#pragma unroll
      for (int p4 = 0; p4 < 4; ++p4) {
        int ip = wave * 4 + p4;
        float4 wv = Wt[ip][kk];
        int4 av = Ad[ip][kk];
        uint2 u00 = *(const uint2*)(xbc + ((unsigned)av.x + lb));
        uint2 u01 = *(const uint2*)(xbc + ((unsigned)av.y + lb));
        uint2 u10 = *(const uint2*)(xbc + ((unsigned)av.z + lb));
        uint2 u11 = *(const uint2*)(xbc + ((unsigned)av.w + lb));

        float s0 = wv.x * bf_lo(u00.x) + wv.y * bf_lo(u01.x) + wv.z * bf_lo(u10.x) + wv.w * bf_lo(u11.x);
        float s1 = wv.x * bf_hi(u00.x) + wv.y * bf_hi(u01.x) + wv.z * bf_hi(u10.x) + wv.w * bf_hi(u11.x);
        float s2 = wv.x * bf_lo(u00.y) + wv.y * bf_lo(u01.y) + wv.z * bf_lo(u10.y) + wv.w * bf_lo(u11.y);
        float s3 = wv.x * bf_hi(u00.y) + wv.y * bf_hi(u01.y) + wv.z * bf_hi(u10.y) + wv.w * bf_hi(u11.y);

        acc[p4][0] += dv.x * s0;
        acc[p4][1] += dv.y * s1;
        acc[p4][2] += dv.z * s2;
        acc[p4][3] += dv.w * s3;
      }
    }
    if (rep < REPS - 1) {
      // keep dummy reps alive (prevents DCE of loads+FMAs)
#pragma unroll
      for (int p4 = 0; p4 < 4; ++p4)
        asm volatile("" :: "v"(acc[p4][0]), "v"(acc[p4][1]),
                           "v"(acc[p4][2]), "v"(acc[p4][3]));
    } else {
#pragma unroll
      for (int p4 = 0; p4 < 4; ++p4)
        *(float4*)&Cs[wave * 4 + p4][c0] =
            make_float4(acc[p4][0], acc[p4][1], acc[p4][2], acc[p4][3]);
    }
  }
  __syncthreads();
  // write-out: thread t = channel, 16 consecutive pixels = 64 B contiguous per thread.
  int ch = threadIdx.x;
  float* ob = out + (size_t)b * CC * HWP + (size_t)ch * HWP + hw0;
#pragma unroll
  for (int p4 = 0; p4 < 4; ++p4) {
    float4 v = make_float4(Cs[p4 * 4 + 0][ch], Cs[p4 * 4 + 1][ch],
                           Cs[p4 * 4 + 2][ch], Cs[p4 * 4 + 3][ch]);
    *(float4*)(ob + p4 * 4) = v;
  }
}

extern "C" void kernel_launch(void* const* d_in, const int* in_sizes, int n_in,
                              void* d_out, int out_size, void* d_ws, size_t ws_size,
                              hipStream_t stream) {
  (void)in_sizes; (void)n_in; (void)out_size; (void)ws_size;
  const float* x     = (const float*)d_in[0];
  const float* pw_w  = (const float*)d_in[1];
  const float* off_w = (const float*)d_in[2];
  const float* off_b = (const float*)d_in[3];
  const float* dw_w  = (const float*)d_in[4];
  float* out = (float*)d_out;

  char* ws = (char*)d_ws;
  unsigned short* xpb = (unsigned short*)ws;            // B*HW*C bf16 = 9,437,184 B
  float* offs = (float*)(ws + 9437184);                 // B*HW*20 f32 = 1,474,560 B

  k_main  <<<576, 256, 0, stream>>>(x, pw_w, off_w, off_b, xpb, offs);
  k_gather<<<1152, 256, 0, stream>>>(xpb, offs, dw_w, out);
}

// Round 6
// 122.038 us; speedup vs baseline: 2.3565x; 2.3565x over previous
//
#include <hip/hip_runtime.h>
#include <hip/hip_bf16.h>

#define HWP 9216   // H*W
#define HH  96
#define WW  96
#define CC  256    // Cin == Cout
#define NB  2

typedef __attribute__((ext_vector_type(8))) short bf16x8;
typedef __attribute__((ext_vector_type(4))) float f32x4;

__device__ inline unsigned short f2bf(float f) {
  union { __hip_bfloat16 h; unsigned short u; } cvt;
  cvt.h = __float2bfloat16(f);
  return cvt.u;
}
__device__ inline float bf_lo(unsigned int u) { return __uint_as_float(u << 16); }
__device__ inline float bf_hi(unsigned int u) { return __uint_as_float(u & 0xffff0000u); }

// ====================== R15 (post-R14 diagnostic) ======================
// MEASURED (R14 REPS=6 probe): k_gather ~23.5us true — MfmaUtil 0,
// VALUBusy 37%, hbm 0.7-2.3% (xpb L2-resident: XCD alignment works),
// Occupancy 31.7% -> LATENCY-BOUND at low occupancy. k_main ~13us.
// Harness workspace-poison fills ~88us of dur_us are FIXED overhead.
// R15: k_gather 16px -> 8px/block (grid 1152 -> 2304, LDS 30.7 -> 19.8KB)
// -> resident blocks/CU ~2.5 -> 8 (waves/CU cap) for ~3x latency hiding.
// PITFALL (R12): cooperative grid.sync under graph capture silently broken
// (absmax 5.28) — never fuse across the xpb producer/consumer boundary.

// ---- fused: xp = pw_w . x  (bf16 MFMA, 32 pix x 256 ch per block, BK=32)
//            + offs = off_w . xp + off_b  (MFMA epilogue on the Cs tile)
// 2-phase dbuf (R11). XCD-aligned: block g -> class e=g%8 produces pixel
// strip [e*1152,(e+1)*1152) per batch; k_gather decode matches.
// Pitfalls kept: MFMA-frag register-prefetch (R6/R7) REGRESSED; BK=64 (R9)
// REGRESSED. Keep BK=32, pad-40 layout (2-way = free).
__global__ __launch_bounds__(256) void k_main(const float* __restrict__ x,
                                              const float* __restrict__ pw_w,
                                              const float* __restrict__ off_w,
                                              const float* __restrict__ off_b,
                                              unsigned short* __restrict__ xpb,
                                              float* __restrict__ offs) {
  __shared__ unsigned short As[2][32 * 40];    // [pix][k] dbuf
  __shared__ unsigned short Bs[2][256 * 40];   // [n][k] dbuf; Bs[0] reused as Cs

  int g   = blockIdx.x;          // 0..575
  int e   = g & 7;
  int idx = g >> 3;              // 0..71
  int b   = idx / 36;
  int m   = idx - b * 36;        // 0..35
  int pix0 = (e * 36 + m) * 32;  // local pixel within batch

  int t    = threadIdx.x;
  int lane = t & 63;
  int w    = t >> 6;
  int mw = (w & 1) * 16;     // wave pixel tile
  int nw = (w >> 1) * 128;   // wave channel half
  int r = lane & 15, q = lane >> 4;

  f32x4 acc[8] = {};

  const float* xg = x + (size_t)b * CC * HWP + pix0;
  int sc = t >> 3;           // channel within 32-chunk
  int sp = (t & 7) * 4;      // pixel offset
  int nB = t >> 2;           // B row within 64-group
  int c8 = (t & 3) * 8;      // B k-offset

  // ---- prologue: stage K-step 0 into buf 0 (B converted inline from f32)
  {
    f32x4 xv = __builtin_nontemporal_load((const f32x4*)(xg + (size_t)sc * HWP + sp));
    As[0][(sp + 0) * 40 + sc] = f2bf(xv.x);
    As[0][(sp + 1) * 40 + sc] = f2bf(xv.y);
    As[0][(sp + 2) * 40 + sc] = f2bf(xv.z);
    As[0][(sp + 3) * 40 + sc] = f2bf(xv.w);
#pragma unroll
    for (int rep = 0; rep < 4; ++rep) {
      int n = rep * 64 + nB;
      const float* wp = pw_w + n * 256 + c8;
      float4 w0 = *(const float4*)wp;
      float4 w1 = *(const float4*)(wp + 4);
      union { ushort4 h[2]; uint4 q4; } pk;
      pk.h[0] = make_ushort4(f2bf(w0.x), f2bf(w0.y), f2bf(w0.z), f2bf(w0.w));
      pk.h[1] = make_ushort4(f2bf(w1.x), f2bf(w1.y), f2bf(w1.z), f2bf(w1.w));
      *(uint4*)&Bs[0][n * 40 + c8] = pk.q4;
    }
  }
  __syncthreads();

  // ---- main loop: 1 barrier per K-step, prefetch t+1 overlapped with MFMA(t)
  for (int kt = 0; kt < 8; ++kt) {
    int cur = kt & 1;
    f32x4 xv;
    float4 b0[4], b1[4];
    bool pre = (kt < 7);
    if (pre) {
      int k0 = (kt + 1) * 32;
      xv = __builtin_nontemporal_load((const f32x4*)(xg + (size_t)(k0 + sc) * HWP + sp));
#pragma unroll
      for (int rep = 0; rep < 4; ++rep) {
        const float* wp = pw_w + (rep * 64 + nB) * 256 + k0 + c8;
        b0[rep] = *(const float4*)wp;
        b1[rep] = *(const float4*)(wp + 4);
      }
    }
    bf16x8 a = *(const bf16x8*)&As[cur][(mw + r) * 40 + q * 8];
#pragma unroll
    for (int nt = 0; nt < 8; ++nt) {
      bf16x8 bb = *(const bf16x8*)&Bs[cur][(nw + nt * 16 + r) * 40 + q * 8];
      acc[nt] = __builtin_amdgcn_mfma_f32_16x16x32_bf16(a, bb, acc[nt], 0, 0, 0);
    }
    if (pre) {
      int nx = cur ^ 1;
      As[nx][(sp + 0) * 40 + sc] = f2bf(xv.x);
      As[nx][(sp + 1) * 40 + sc] = f2bf(xv.y);
      As[nx][(sp + 2) * 40 + sc] = f2bf(xv.z);
      As[nx][(sp + 3) * 40 + sc] = f2bf(xv.w);
#pragma unroll
      for (int rep = 0; rep < 4; ++rep) {
        int n = rep * 64 + nB;
        union { ushort4 h[2]; uint4 q4; } pk;
        pk.h[0] = make_ushort4(f2bf(b0[rep].x), f2bf(b0[rep].y), f2bf(b0[rep].z), f2bf(b0[rep].w));
        pk.h[1] = make_ushort4(f2bf(b1[rep].x), f2bf(b1[rep].y), f2bf(b1[rep].z), f2bf(b1[rep].w));
        *(uint4*)&Bs[nx][n * 40 + c8] = pk.q4;
      }
    }
    __syncthreads();
  }

  // Cs aliases Bs[0]: last K-step read buf 1; final sync drained buf 0 reads.
  unsigned short* Cs = &Bs[0][0];   // [pix][ch] bf16, pad 264

  // C/D: col = lane&15 (ch), row = q*4+rr (pix) -> Cs[pix][ch] bf16
#pragma unroll
  for (int nt = 0; nt < 8; ++nt)
#pragma unroll
    for (int rr = 0; rr < 4; ++rr)
      Cs[(mw + q * 4 + rr) * 264 + nw + nt * 16 + r] = f2bf(acc[nt][rr]);
  __syncthreads();

  // write xpb coalesced: 64 B contiguous per thread
  {
    int pix = t >> 3, c32 = (t & 7) * 32;
    unsigned short* o = xpb + ((size_t)b * HWP + pix0 + pix) * CC + c32;
#pragma unroll
    for (int j = 0; j < 4; ++j)
      *(uint4*)(o + j * 8) = *(const uint4*)&Cs[pix * 264 + c32 + j * 8];
  }

  // offset epilogue: offs[pix, o] = sum_c Cs[pix][c] * off_w[o][c] + off_b[o]
  {
    int mw2 = (w & 1) * 16;    // pixel tile
    int nw2 = (w >> 1) * 16;   // o tile (0 or 16)
    int row = nw2 + r;
    f32x4 oacc = {};
#pragma unroll
    for (int ks = 0; ks < CC; ks += 32) {
      bf16x8 a = *(const bf16x8*)&Cs[(mw2 + r) * 264 + ks + q * 8];
      bf16x8 bb = {};
      if (row < 18) {
        const float* wp = off_w + row * 256 + ks + q * 8;
        float4 w0 = *(const float4*)wp;
        float4 w1 = *(const float4*)(wp + 4);
        union { unsigned short u[8]; bf16x8 v; } pk;
        pk.u[0] = f2bf(w0.x); pk.u[1] = f2bf(w0.y); pk.u[2] = f2bf(w0.z); pk.u[3] = f2bf(w0.w);
        pk.u[4] = f2bf(w1.x); pk.u[5] = f2bf(w1.y); pk.u[6] = f2bf(w1.z); pk.u[7] = f2bf(w1.w);
        bb = pk.v;
      }
      oacc = __builtin_amdgcn_mfma_f32_16x16x32_bf16(a, bb, oacc, 0, 0, 0);
    }
    if (row < 18) {
      float ob = off_b[row];
      size_t base = ((size_t)b * HWP + pix0 + mw2 + q * 4) * 20 + row;
#pragma unroll
      for (int rr = 0; rr < 4; ++rr)
        offs[base + (size_t)rr * 20] = oacc[rr] + ob;
    }
  }
}

// ---- gather + depthwise: R15 = 8 pixels/block, 2 px/wave, grid 2304.
// Rationale (R14 counters): latency-bound, Occupancy 31.7% — this triples
// resident blocks/CU (LDS 19.8KB, VGPR ~55 -> 8 blocks/CU by wave cap).
// Per-output math order unchanged -> bit-identical results.
// XCD-aligned to k_main strips: c = e*144+m, px [8c,8c+8) within class-e
// strip. 8 | 96 so a chunk never crosses a row.
// Hard-won pitfalls:
//  * NO launch-bounds min-wave arg (R6: forced VGPR 64 -> scratch spills, 3x)
//  * NO nontemporal output stores (R4: 4x WRITE_SIZE amplification)
//  * NO 8-ch/lane half-wave scheme (R8: VGPR 176, occupancy 9%, +25% time)
__global__ __launch_bounds__(256) void k_gather(const unsigned short* __restrict__ xp,
                                                const float* __restrict__ offs,
                                                const float* __restrict__ dw_w,
                                                float* __restrict__ out) {
  __shared__ float Cs[8][257];
  __shared__ float4 Wt[8][9];    // bilinear weights per (pixel, tap)
  __shared__ int4   Ad[8][9];    // corner row byte-offsets per (pixel, tap)
  __shared__ float  dvs[9][257]; // dw_w transposed [tap][ch]

  // XCD-aligned decode: g -> (e, b, m2); chunk c = e*144 + m2 (8 px each)
  int g   = blockIdx.x;          // 0..2303
  int e   = g & 7;
  int idx = g >> 3;              // 0..287
  int b   = idx / 144;
  int m2  = idx - b * 144;       // 0..143
  int c   = e * 144 + m2;        // 0..1151
  int hw0 = c * 8;               // pixel within batch
  int pix0 = b * HWP + hw0;      // global pixel

  int wave = threadIdx.x >> 6;
  int lane = threadIdx.x & 63;
  int c0 = lane * 4;

  const unsigned short* xb = xp + (size_t)b * HWP * CC;
  const float* opb = offs + (size_t)pix0 * 20;

  // ---- phase 0a: stage dw_w transposed (9 scalar loads/thread)
  {
    int t = threadIdx.x;
#pragma unroll
    for (int kk = 0; kk < 9; ++kk)
      dvs[kk][t] = dw_w[t * 9 + kk];
  }

  // ---- phase 0b: 72 threads compute the wave-uniform per-(pixel,tap) data
  {
    int tp = threadIdx.x;
    if (tp < 72) {
      int ip = tp / 9;               // pixel 0..7
      int kk = tp - ip * 9;          // tap 0..8
      int hw = hw0 + ip;
      int h = hw / WW;
      int wq = hw - h * WW;
      float2 o2 = *(const float2*)(opb + ip * 20 + 2 * kk);
      float y = (float)(h + kk / 3 - 1) + o2.x;
      float x = (float)(wq + kk % 3 - 1) + o2.y;
      float y0f = floorf(y), x0f = floorf(x);
      float fy = y - y0f, fx = x - x0f;
      int y0 = (int)y0f, x0 = (int)x0f;
      int y1 = y0 + 1, x1 = x0 + 1;
      bool vy0 = (y0 >= 0) & (y0 < HH);
      bool vy1 = (y1 >= 0) & (y1 < HH);
      bool vx0 = (x0 >= 0) & (x0 < WW);
      bool vx1 = (x1 >= 0) & (x1 < WW);
      int y0c = y0 < 0 ? 0 : (y0 > HH - 1 ? HH - 1 : y0);
      int y1c = y1 < 0 ? 0 : (y1 > HH - 1 ? HH - 1 : y1);
      int x0c = x0 < 0 ? 0 : (x0 > WW - 1 ? WW - 1 : x0);
      int x1c = x1 < 0 ? 0 : (x1 > WW - 1 ? WW - 1 : x1);
      Wt[ip][kk] = make_float4(
          (1.f - fy) * (1.f - fx) * ((vy0 && vx0) ? 1.f : 0.f),
          (1.f - fy) * fx         * ((vy0 && vx1) ? 1.f : 0.f),
          fy * (1.f - fx)         * ((vy1 && vx0) ? 1.f : 0.f),
          fy * fx                 * ((vy1 && vx1) ? 1.f : 0.f));
      Ad[ip][kk] = make_int4((y0c * WW + x0c) * (CC * 2), (y0c * WW + x1c) * (CC * 2),
                             (y1c * WW + x0c) * (CC * 2), (y1c * WW + x1c) * (CC * 2));
    }
  }
  __syncthreads();

  // ---- main loop: per-channel work only; addresses/weights from LDS
  const char* xbc = (const char*)xb;
  unsigned lb = (unsigned)(lane * 8);   // this lane's 4-channel byte offset

  float acc[2][4] = {};
#pragma unroll
  for (int kk = 0; kk < 9; ++kk) {
    float4 dv = *(const float4*)&dvs[kk][c0];
#pragma unroll
    for (int p2 = 0; p2 < 2; ++p2) {
      int ip = wave * 2 + p2;
      float4 wv = Wt[ip][kk];
      int4 av = Ad[ip][kk];
      uint2 u00 = *(const uint2*)(xbc + ((unsigned)av.x + lb));
      uint2 u01 = *(const uint2*)(xbc + ((unsigned)av.y + lb));
      uint2 u10 = *(const uint2*)(xbc + ((unsigned)av.z + lb));
      uint2 u11 = *(const uint2*)(xbc + ((unsigned)av.w + lb));

      float s0 = wv.x * bf_lo(u00.x) + wv.y * bf_lo(u01.x) + wv.z * bf_lo(u10.x) + wv.w * bf_lo(u11.x);
      float s1 = wv.x * bf_hi(u00.x) + wv.y * bf_hi(u01.x) + wv.z * bf_hi(u10.x) + wv.w * bf_hi(u11.x);
      float s2 = wv.x * bf_lo(u00.y) + wv.y * bf_lo(u01.y) + wv.z * bf_lo(u10.y) + wv.w * bf_lo(u11.y);
      float s3 = wv.x * bf_hi(u00.y) + wv.y * bf_hi(u01.y) + wv.z * bf_hi(u10.y) + wv.w * bf_hi(u11.y);

      acc[p2][0] += dv.x * s0;
      acc[p2][1] += dv.y * s1;
      acc[p2][2] += dv.z * s2;
      acc[p2][3] += dv.w * s3;
    }
  }
#pragma unroll
  for (int p2 = 0; p2 < 2; ++p2)
    *(float4*)&Cs[wave * 2 + p2][c0] =
        make_float4(acc[p2][0], acc[p2][1], acc[p2][2], acc[p2][3]);
  __syncthreads();
  // write-out: thread t = channel, 8 consecutive pixels = 32 B contiguous.
  int ch = threadIdx.x;
  float* ob = out + (size_t)b * CC * HWP + (size_t)ch * HWP + hw0;
  *(float4*)(ob + 0) = make_float4(Cs[0][ch], Cs[1][ch], Cs[2][ch], Cs[3][ch]);
  *(float4*)(ob + 4) = make_float4(Cs[4][ch], Cs[5][ch], Cs[6][ch], Cs[7][ch]);
}

extern "C" void kernel_launch(void* const* d_in, const int* in_sizes, int n_in,
                              void* d_out, int out_size, void* d_ws, size_t ws_size,
                              hipStream_t stream) {
  (void)in_sizes; (void)n_in; (void)out_size; (void)ws_size;
  const float* x     = (const float*)d_in[0];
  const float* pw_w  = (const float*)d_in[1];
  const float* off_w = (const float*)d_in[2];
  const float* off_b = (const float*)d_in[3];
  const float* dw_w  = (const float*)d_in[4];
  float* out = (float*)d_out;

  char* ws = (char*)d_ws;
  unsigned short* xpb = (unsigned short*)ws;            // B*HW*C bf16 = 9,437,184 B
  float* offs = (float*)(ws + 9437184);                 // B*HW*20 f32 = 1,474,560 B

  k_main  <<<576, 256, 0, stream>>>(x, pw_w, off_w, off_b, xpb, offs);
  k_gather<<<2304, 256, 0, stream>>>(xpb, offs, dw_w, out);
}

// Round 7
// 116.901 us; speedup vs baseline: 2.4600x; 1.0439x over previous
//
#include <hip/hip_runtime.h>
#include <hip/hip_bf16.h>

#define HWP 9216   // H*W
#define HH  96
#define WW  96
#define CC  256    // Cin == Cout
#define NB  2

typedef __attribute__((ext_vector_type(8))) short bf16x8;
typedef __attribute__((ext_vector_type(4))) float f32x4;

__device__ inline unsigned short f2bf(float f) {
  union { __hip_bfloat16 h; unsigned short u; } cvt;
  cvt.h = __float2bfloat16(f);
  return cvt.u;
}
__device__ inline float bf_lo(unsigned int u) { return __uint_as_float(u << 16); }
__device__ inline float bf_hi(unsigned int u) { return __uint_as_float(u & 0xffff0000u); }

// ====================== R16 ======================
// MEASURED (R14 probe): k_gather ~21-24us (MfmaUtil 0, VALUBusy 37%@2.5blk/CU,
// hbm ~1% — xpb is L2-resident), k_main ~13us, harness fills ~88us FIXED.
// R15 (8px/block, 8 blocks/CU): -2.9us only -> NOT purely TLP-bound; theory:
// VMEM-instruction/L1-transaction bound (72 uint2 gathers/thread).
// R16: half-wave pixel split — lanes 0-31 = px0, lanes 32-63 = px1, 8 ch/lane,
// corner loads uint4 (dwordx4): 36 loads/thread (was 72), same bytes, same
// math order (bit-identical). R8's 8-ch pitfall was VGPR-176 occupancy
// collapse in the 16px structure; here VGPR ~70-80, LDS 19.8KB -> still 8
// blocks/CU.
// PITFALL (R12): cooperative grid.sync under graph capture silently broken
// (absmax 5.28) — never fuse across the xpb producer/consumer boundary.

// ---- fused: xp = pw_w . x  (bf16 MFMA, 32 pix x 256 ch per block, BK=32)
//            + offs = off_w . xp + off_b  (MFMA epilogue on the Cs tile)
// 2-phase dbuf (R11). XCD-aligned: block g -> class e=g%8 produces pixel
// strip [e*1152,(e+1)*1152) per batch; k_gather decode matches.
// Pitfalls kept: MFMA-frag register-prefetch (R6/R7) REGRESSED; BK=64 (R9)
// REGRESSED. Keep BK=32, pad-40 layout (2-way = free).
__global__ __launch_bounds__(256) void k_main(const float* __restrict__ x,
                                              const float* __restrict__ pw_w,
                                              const float* __restrict__ off_w,
                                              const float* __restrict__ off_b,
                                              unsigned short* __restrict__ xpb,
                                              float* __restrict__ offs) {
  __shared__ unsigned short As[2][32 * 40];    // [pix][k] dbuf
  __shared__ unsigned short Bs[2][256 * 40];   // [n][k] dbuf; Bs[0] reused as Cs

  int g   = blockIdx.x;          // 0..575
  int e   = g & 7;
  int idx = g >> 3;              // 0..71
  int b   = idx / 36;
  int m   = idx - b * 36;        // 0..35
  int pix0 = (e * 36 + m) * 32;  // local pixel within batch

  int t    = threadIdx.x;
  int lane = t & 63;
  int w    = t >> 6;
  int mw = (w & 1) * 16;     // wave pixel tile
  int nw = (w >> 1) * 128;   // wave channel half
  int r = lane & 15, q = lane >> 4;

  f32x4 acc[8] = {};

  const float* xg = x + (size_t)b * CC * HWP + pix0;
  int sc = t >> 3;           // channel within 32-chunk
  int sp = (t & 7) * 4;      // pixel offset
  int nB = t >> 2;           // B row within 64-group
  int c8 = (t & 3) * 8;      // B k-offset

  // ---- prologue: stage K-step 0 into buf 0 (B converted inline from f32)
  {
    f32x4 xv = __builtin_nontemporal_load((const f32x4*)(xg + (size_t)sc * HWP + sp));
    As[0][(sp + 0) * 40 + sc] = f2bf(xv.x);
    As[0][(sp + 1) * 40 + sc] = f2bf(xv.y);
    As[0][(sp + 2) * 40 + sc] = f2bf(xv.z);
    As[0][(sp + 3) * 40 + sc] = f2bf(xv.w);
#pragma unroll
    for (int rep = 0; rep < 4; ++rep) {
      int n = rep * 64 + nB;
      const float* wp = pw_w + n * 256 + c8;
      float4 w0 = *(const float4*)wp;
      float4 w1 = *(const float4*)(wp + 4);
      union { ushort4 h[2]; uint4 q4; } pk;
      pk.h[0] = make_ushort4(f2bf(w0.x), f2bf(w0.y), f2bf(w0.z), f2bf(w0.w));
      pk.h[1] = make_ushort4(f2bf(w1.x), f2bf(w1.y), f2bf(w1.z), f2bf(w1.w));
      *(uint4*)&Bs[0][n * 40 + c8] = pk.q4;
    }
  }
  __syncthreads();

  // ---- main loop: 1 barrier per K-step, prefetch t+1 overlapped with MFMA(t)
  for (int kt = 0; kt < 8; ++kt) {
    int cur = kt & 1;
    f32x4 xv;
    float4 b0[4], b1[4];
    bool pre = (kt < 7);
    if (pre) {
      int k0 = (kt + 1) * 32;
      xv = __builtin_nontemporal_load((const f32x4*)(xg + (size_t)(k0 + sc) * HWP + sp));
#pragma unroll
      for (int rep = 0; rep < 4; ++rep) {
        const float* wp = pw_w + (rep * 64 + nB) * 256 + k0 + c8;
        b0[rep] = *(const float4*)wp;
        b1[rep] = *(const float4*)(wp + 4);
      }
    }
    bf16x8 a = *(const bf16x8*)&As[cur][(mw + r) * 40 + q * 8];
#pragma unroll
    for (int nt = 0; nt < 8; ++nt) {
      bf16x8 bb = *(const bf16x8*)&Bs[cur][(nw + nt * 16 + r) * 40 + q * 8];
      acc[nt] = __builtin_amdgcn_mfma_f32_16x16x32_bf16(a, bb, acc[nt], 0, 0, 0);
    }
    if (pre) {
      int nx = cur ^ 1;
      As[nx][(sp + 0) * 40 + sc] = f2bf(xv.x);
      As[nx][(sp + 1) * 40 + sc] = f2bf(xv.y);
      As[nx][(sp + 2) * 40 + sc] = f2bf(xv.z);
      As[nx][(sp + 3) * 40 + sc] = f2bf(xv.w);
#pragma unroll
      for (int rep = 0; rep < 4; ++rep) {
        int n = rep * 64 + nB;
        union { ushort4 h[2]; uint4 q4; } pk;
        pk.h[0] = make_ushort4(f2bf(b0[rep].x), f2bf(b0[rep].y), f2bf(b0[rep].z), f2bf(b0[rep].w));
        pk.h[1] = make_ushort4(f2bf(b1[rep].x), f2bf(b1[rep].y), f2bf(b1[rep].z), f2bf(b1[rep].w));
        *(uint4*)&Bs[nx][n * 40 + c8] = pk.q4;
      }
    }
    __syncthreads();
  }

  // Cs aliases Bs[0]: last K-step read buf 1; final sync drained buf 0 reads.
  unsigned short* Cs = &Bs[0][0];   // [pix][ch] bf16, pad 264

  // C/D: col = lane&15 (ch), row = q*4+rr (pix) -> Cs[pix][ch] bf16
#pragma unroll
  for (int nt = 0; nt < 8; ++nt)
#pragma unroll
    for (int rr = 0; rr < 4; ++rr)
      Cs[(mw + q * 4 + rr) * 264 + nw + nt * 16 + r] = f2bf(acc[nt][rr]);
  __syncthreads();

  // write xpb coalesced: 64 B contiguous per thread
  {
    int pix = t >> 3, c32 = (t & 7) * 32;
    unsigned short* o = xpb + ((size_t)b * HWP + pix0 + pix) * CC + c32;
#pragma unroll
    for (int j = 0; j < 4; ++j)
      *(uint4*)(o + j * 8) = *(const uint4*)&Cs[pix * 264 + c32 + j * 8];
  }

  // offset epilogue: offs[pix, o] = sum_c Cs[pix][c] * off_w[o][c] + off_b[o]
  {
    int mw2 = (w & 1) * 16;    // pixel tile
    int nw2 = (w >> 1) * 16;   // o tile (0 or 16)
    int row = nw2 + r;
    f32x4 oacc = {};
#pragma unroll
    for (int ks = 0; ks < CC; ks += 32) {
      bf16x8 a = *(const bf16x8*)&Cs[(mw2 + r) * 264 + ks + q * 8];
      bf16x8 bb = {};
      if (row < 18) {
        const float* wp = off_w + row * 256 + ks + q * 8;
        float4 w0 = *(const float4*)wp;
        float4 w1 = *(const float4*)(wp + 4);
        union { unsigned short u[8]; bf16x8 v; } pk;
        pk.u[0] = f2bf(w0.x); pk.u[1] = f2bf(w0.y); pk.u[2] = f2bf(w0.z); pk.u[3] = f2bf(w0.w);
        pk.u[4] = f2bf(w1.x); pk.u[5] = f2bf(w1.y); pk.u[6] = f2bf(w1.z); pk.u[7] = f2bf(w1.w);
        bb = pk.v;
      }
      oacc = __builtin_amdgcn_mfma_f32_16x16x32_bf16(a, bb, oacc, 0, 0, 0);
    }
    if (row < 18) {
      float ob = off_b[row];
      size_t base = ((size_t)b * HWP + pix0 + mw2 + q * 4) * 20 + row;
#pragma unroll
      for (int rr = 0; rr < 4; ++rr)
        offs[base + (size_t)rr * 20] = oacc[rr] + ob;
    }
  }
}

// ---- gather + depthwise: R16 = 8 px/block, half-wave pixel split.
// Lanes 0-31 own pixel wave*2, lanes 32-63 own pixel wave*2+1; each lane
// covers 8 consecutive channels via uint4 (dwordx4) corner loads ->
// 36 VMEM loads/thread (was 72), same bytes, same per-channel math order
// (bit-identical output). Wt/Ad broadcast reads per half-wave.
// Hard-won pitfalls:
//  * NO launch-bounds min-wave arg (R6: forced VGPR 64 -> scratch spills, 3x)
//  * NO nontemporal output stores (R4: 4x WRITE_SIZE amplification)
//  * R8 (8ch/lane VGPR-176 collapse) does NOT apply here: acc stays 8 floats.
__global__ __launch_bounds__(256) void k_gather(const unsigned short* __restrict__ xp,
                                                const float* __restrict__ offs,
                                                const float* __restrict__ dw_w,
                                                float* __restrict__ out) {
  __shared__ float Cs[8][257];
  __shared__ float4 Wt[8][9];    // bilinear weights per (pixel, tap)
  __shared__ int4   Ad[8][9];    // corner row byte-offsets per (pixel, tap)
  __shared__ float  dvs[9][257]; // dw_w transposed [tap][ch]

  // XCD-aligned decode: g -> (e, b, m2); chunk c = e*144 + m2 (8 px each)
  int g   = blockIdx.x;          // 0..2303
  int e   = g & 7;
  int idx = g >> 3;              // 0..287
  int b   = idx / 144;
  int m2  = idx - b * 144;       // 0..143
  int c   = e * 144 + m2;        // 0..1151
  int hw0 = c * 8;               // pixel within batch
  int pix0 = b * HWP + hw0;      // global pixel

  int wave = threadIdx.x >> 6;
  int lane = threadIdx.x & 63;
  int hp   = lane >> 5;          // half-wave pixel select (0/1)
  int hl   = lane & 31;          // lane within half-wave
  int ip   = wave * 2 + hp;      // this lane's pixel 0..7
  int c0   = hl * 8;             // this lane's 8-channel base

  const unsigned short* xb = xp + (size_t)b * HWP * CC;
  const float* opb = offs + (size_t)pix0 * 20;

  // ---- phase 0a: stage dw_w transposed (9 scalar loads/thread)
  {
    int t = threadIdx.x;
#pragma unroll
    for (int kk = 0; kk < 9; ++kk)
      dvs[kk][t] = dw_w[t * 9 + kk];
  }

  // ---- phase 0b: 72 threads compute the wave-uniform per-(pixel,tap) data
  {
    int tp = threadIdx.x;
    if (tp < 72) {
      int ipp = tp / 9;              // pixel 0..7
      int kk = tp - ipp * 9;         // tap 0..8
      int hw = hw0 + ipp;
      int h = hw / WW;
      int wq = hw - h * WW;
      float2 o2 = *(const float2*)(opb + ipp * 20 + 2 * kk);
      float y = (float)(h + kk / 3 - 1) + o2.x;
      float x = (float)(wq + kk % 3 - 1) + o2.y;
      float y0f = floorf(y), x0f = floorf(x);
      float fy = y - y0f, fx = x - x0f;
      int y0 = (int)y0f, x0 = (int)x0f;
      int y1 = y0 + 1, x1 = x0 + 1;
      bool vy0 = (y0 >= 0) & (y0 < HH);
      bool vy1 = (y1 >= 0) & (y1 < HH);
      bool vx0 = (x0 >= 0) & (x0 < WW);
      bool vx1 = (x1 >= 0) & (x1 < WW);
      int y0c = y0 < 0 ? 0 : (y0 > HH - 1 ? HH - 1 : y0);
      int y1c = y1 < 0 ? 0 : (y1 > HH - 1 ? HH - 1 : y1);
      int x0c = x0 < 0 ? 0 : (x0 > WW - 1 ? WW - 1 : x0);
      int x1c = x1 < 0 ? 0 : (x1 > WW - 1 ? WW - 1 : x1);
      Wt[ipp][kk] = make_float4(
          (1.f - fy) * (1.f - fx) * ((vy0 && vx0) ? 1.f : 0.f),
          (1.f - fy) * fx         * ((vy0 && vx1) ? 1.f : 0.f),
          fy * (1.f - fx)         * ((vy1 && vx0) ? 1.f : 0.f),
          fy * fx                 * ((vy1 && vx1) ? 1.f : 0.f));
      Ad[ipp][kk] = make_int4((y0c * WW + x0c) * (CC * 2), (y0c * WW + x1c) * (CC * 2),
                              (y1c * WW + x0c) * (CC * 2), (y1c * WW + x1c) * (CC * 2));
    }
  }
  __syncthreads();

  // ---- main loop: 4 uint4 corner loads per tap; unpack + FMA only.
  const char* xbc = (const char*)xb;
  unsigned lb = (unsigned)(hl * 16);   // this lane's 8-channel byte offset

  float acc[8] = {};
#pragma unroll
  for (int kk = 0; kk < 9; ++kk) {
    float4 dv0 = *(const float4*)&dvs[kk][c0];
    float4 dv1 = *(const float4*)&dvs[kk][c0 + 4];
    float4 wv = Wt[ip][kk];
    int4 av = Ad[ip][kk];
    uint4 u00 = *(const uint4*)(xbc + ((unsigned)av.x + lb));
    uint4 u01 = *(const uint4*)(xbc + ((unsigned)av.y + lb));
    uint4 u10 = *(const uint4*)(xbc + ((unsigned)av.z + lb));
    uint4 u11 = *(const uint4*)(xbc + ((unsigned)av.w + lb));
    const unsigned* p00 = (const unsigned*)&u00;
    const unsigned* p01 = (const unsigned*)&u01;
    const unsigned* p10 = (const unsigned*)&u10;
    const unsigned* p11 = (const unsigned*)&u11;
    float dvv[8] = {dv0.x, dv0.y, dv0.z, dv0.w, dv1.x, dv1.y, dv1.z, dv1.w};
#pragma unroll
    for (int j = 0; j < 4; ++j) {
      unsigned w00 = p00[j], w01 = p01[j], w10 = p10[j], w11 = p11[j];
      float slo = wv.x * bf_lo(w00) + wv.y * bf_lo(w01) + wv.z * bf_lo(w10) + wv.w * bf_lo(w11);
      float shi = wv.x * bf_hi(w00) + wv.y * bf_hi(w01) + wv.z * bf_hi(w10) + wv.w * bf_hi(w11);
      acc[2 * j]     += dvv[2 * j]     * slo;
      acc[2 * j + 1] += dvv[2 * j + 1] * shi;
    }
  }
  *(float4*)&Cs[ip][c0]     = make_float4(acc[0], acc[1], acc[2], acc[3]);
  *(float4*)&Cs[ip][c0 + 4] = make_float4(acc[4], acc[5], acc[6], acc[7]);
  __syncthreads();
  // write-out: thread t = channel, 8 consecutive pixels = 32 B contiguous.
  int ch = threadIdx.x;
  float* ob = out + (size_t)b * CC * HWP + (size_t)ch * HWP + hw0;
  *(float4*)(ob + 0) = make_float4(Cs[0][ch], Cs[1][ch], Cs[2][ch], Cs[3][ch]);
  *(float4*)(ob + 4) = make_float4(Cs[4][ch], Cs[5][ch], Cs[6][ch], Cs[7][ch]);
}

extern "C" void kernel_launch(void* const* d_in, const int* in_sizes, int n_in,
                              void* d_out, int out_size, void* d_ws, size_t ws_size,
                              hipStream_t stream) {
  (void)in_sizes; (void)n_in; (void)out_size; (void)ws_size;
  const float* x     = (const float*)d_in[0];
  const float* pw_w  = (const float*)d_in[1];
  const float* off_w = (const float*)d_in[2];
  const float* off_b = (const float*)d_in[3];
  const float* dw_w  = (const float*)d_in[4];
  float* out = (float*)d_out;

  char* ws = (char*)d_ws;
  unsigned short* xpb = (unsigned short*)ws;            // B*HW*C bf16 = 9,437,184 B
  float* offs = (float*)(ws + 9437184);                 // B*HW*20 f32 = 1,474,560 B

  k_main  <<<576, 256, 0, stream>>>(x, pw_w, off_w, off_b, xpb, offs);
  k_gather<<<2304, 256, 0, stream>>>(xpb, offs, dw_w, out);
}